// Round 11
// baseline (457.308 us; speedup 1.0000x reference)
//
#include <hip/hip_runtime.h>
#include <hip/hip_bf16.h>
#include <cstdint>

typedef __attribute__((ext_vector_type(8))) short short8;
typedef __attribute__((ext_vector_type(4))) float f32x4;
typedef __attribute__((ext_vector_type(8))) unsigned short ushort8;

#define B_ 16
#define T_ 2048
#define D_ 1024
#define M_ (B_*T_)   // 32768
#define NC 32        // scan chunks
#define CL 64        // chunk length = T_/NC

static __device__ __forceinline__ float bf2f(unsigned short u) {
  unsigned int x = ((unsigned int)u) << 16;
  return __builtin_bit_cast(float, x);
}
static __device__ __forceinline__ unsigned short f2bf(float f) {
  unsigned int x = __builtin_bit_cast(unsigned int, f);
  unsigned int r = x + 0x7fffu + ((x >> 16) & 1u);
  return (unsigned short)(r >> 16);
}
static __device__ __forceinline__ float sigmoidf(float v) {
  return 1.f / (1.f + __expf(-v));
}

typedef const __attribute__((address_space(1))) unsigned int* gas1_t;
typedef __attribute__((address_space(3))) unsigned int* las3_t;
static __device__ __forceinline__ void async_copy16(const void* g, void* l) {
  __builtin_amdgcn_global_load_lds((gas1_t)g, (las3_t)l, 16, 0, 0);
}

#define VMCNT8 asm volatile("s_waitcnt vmcnt(8)" ::: "memory")
#define VMCNT6 asm volatile("s_waitcnt vmcnt(6)" ::: "memory")
#define VMCNT4 asm volatile("s_waitcnt vmcnt(4)" ::: "memory")
#define VMCNT2 asm volatile("s_waitcnt vmcnt(2)" ::: "memory")
#define VMCNT0 asm volatile("s_waitcnt vmcnt(0)" ::: "memory")
#define LGKM0  asm volatile("s_waitcnt lgkmcnt(0)" ::: "memory")
#define SBAR   __builtin_amdgcn_s_barrier()
#define SCHED0 __builtin_amdgcn_sched_barrier(0)

// ---------------- merged fp32 -> bf16 converts (x8 vectorized, grid-stride) -------
__global__ void cvt_all(const float* __restrict__ x,  unsigned short* __restrict__ xb,
                        const float* __restrict__ w1, unsigned short* __restrict__ o1,
                        const float* __restrict__ w2, unsigned short* __restrict__ o2,
                        const float* __restrict__ w3, unsigned short* __restrict__ o3) {
  long i = (long)blockIdx.x * blockDim.x + threadIdx.x;
  long stride = (long)gridDim.x * blockDim.x;
  for (; i < 4718592; i += stride) {
    const float* src; unsigned short* dst; long off;
    if (i < 4194304)      { src = x;  dst = xb; off = i; }
    else if (i < 4456448) { src = w1; dst = o1; off = i - 4194304; }
    else if (i < 4587520) { src = w2; dst = o2; off = i - 4456448; }
    else                  { src = w3; dst = o3; off = i - 4587520; }
    const float4* p = (const float4*)(src + off * 8);
    float4 a = p[0], b = p[1];
    ushort8 o;
    o[0] = f2bf(a.x); o[1] = f2bf(a.y); o[2] = f2bf(a.z); o[3] = f2bf(a.w);
    o[4] = f2bf(b.x); o[5] = f2bf(b.y); o[6] = f2bf(b.z); o[7] = f2bf(b.w);
    *(ushort8*)(dst + off * 8) = o;
  }
}

// ---------------- 256x256 read-consume bf16 GEMM, 2-tile unrolled -----------------
// == R10 structure with compile-time CUR/NL (addresses fold into ds offsets) ==
// 3 phases/tile: {ds_reads | stage issue} BAR lgkm0 {MFMA cluster} vmcnt BAR
//   Q0: rd A0(8)+B0(4) | stage A0',B0'(nxt) | MM(00)        | vmcnt(6)
//   Q1: rd B1(4)       | stage B1',A1'(nxt) | MM(01)        | vmcnt(8)
//   Q2: rd A1(8, overwrite A-set)           | MM(10)+MM(11) | vmcnt(4)
// Ledger: end-Q2 vmcnt(4) drains A0',B0'(t+1) for Q0; end-Q0 vmcnt(6) drains
//   B1(t); end-Q1 vmcnt(8) drains A1(t). Never < 4 outstanding mid-loop (T4).
//   Tail tile: vmcnt(2)/vmcnt(0). Prologue: 4 half-tiles, vmcnt(4).
template<int EPI>
__global__ __launch_bounds__(512, 2) void gemm256(
    const unsigned short* __restrict__ A, long lda,
    const unsigned short* __restrict__ Bw,
    const float* __restrict__ bias,
    void* __restrict__ Cout, long ldc,
    int nbx)
{
  constexpr int KT = 16;
  __shared__ __align__(16) unsigned short lds[65536];  // 128 KiB

  const int tid = threadIdx.x;
  const int l  = tid & 63, w = tid >> 6;
  const int wm = w >> 2, wn = w & 3;
  const int fr = l & 15, g = l >> 4;
  const int t8 = tid >> 3;
  const int c8x = ((l & 7) ^ (l >> 3)) << 4;     // staging source XOR (bytes)
  const int s0 = ((g ^ (fr & 7)) << 4);          // ds_read swizzle, kk=0
  const int aoff  = wm * 8192 + fr * 128 + s0;   // A frag base (within half), kk=0
  const int aoff1 = aoff ^ 0x40;                 // kk=1 (XOR, not add!)
  const int boff  = 65536 + wn * 4096 + fr * 128 + s0;  // B frag base, kk=0
  const int boff1 = boff ^ 0x40;                 // kk=1
  const int tB = (w >> 2) * 64 + (w & 3) * 8 + (l >> 3);

  const int nwg = gridDim.x;
  const int cpx = nwg >> 3;
  const int bid = blockIdx.x;
  const int swz = (bid & 7) * cpx + (bid >> 3);
  const long m0 = (long)(swz / nbx) * 256;
  const long n0 = (long)(swz % nbx) * 256;

  const char* Ab = (const char*)A;
  const char* Bb = (const char*)Bw;
  const long ldab = lda * 2;
  char* LB = (char*)lds;

  auto stA = [&](int kt, int h, int nb) {
    char* lb = LB + nb * 32768 + h * 16384 + w * 1024;
    long col = (long)kt * 128 + c8x;
    async_copy16(Ab + (m0 + h * 64 + t8) * ldab + col, lb);
    async_copy16(Ab + (m0 + 128 + h * 64 + t8) * ldab + col, lb + 8192);
  };
  auto stB = [&](int kt, int h, int nb) {
    char* lb = LB + 65536 + nb * 32768 + h * 16384 + w * 1024;
    long col = (long)kt * 128 + c8x;
    async_copy16(Bb + (n0 + tB + h * 32) * 2048 + col, lb);
    async_copy16(Bb + (n0 + tB + 128 + h * 32) * 2048 + col, lb + 8192);
  };

  f32x4 acc[8][4] = {};
  short8 af[4][2], bf0[2][2], bf1[2][2];

#define RD_A(DST, MH, CUR) do {                                                \
    const char* p0_ = LB + (CUR) * 32768 + (MH) * 16384 + aoff;                \
    const char* p1_ = LB + (CUR) * 32768 + (MH) * 16384 + aoff1;               \
    _Pragma("unroll") for (int mi = 0; mi < 4; ++mi) {                         \
      DST[mi][0] = *(const short8*)(p0_ + mi * 2048);                          \
      DST[mi][1] = *(const short8*)(p1_ + mi * 2048); }                        \
  } while (0)
#define RD_B(DST, NH, CUR) do {                                                \
    const char* p0_ = LB + (CUR) * 32768 + (NH) * 16384 + boff;                \
    const char* p1_ = LB + (CUR) * 32768 + (NH) * 16384 + boff1;               \
    _Pragma("unroll") for (int ni = 0; ni < 2; ++ni) {                         \
      DST[ni][0] = *(const short8*)(p0_ + ni * 2048);                          \
      DST[ni][1] = *(const short8*)(p1_ + ni * 2048); }                        \
  } while (0)
#define MM(AF, BF, MB, NB) do {                                                \
    __builtin_amdgcn_s_setprio(1);                                             \
    _Pragma("unroll") for (int mi = 0; mi < 4; ++mi)                           \
    _Pragma("unroll") for (int ni = 0; ni < 2; ++ni) {                         \
      acc[(MB)+mi][(NB)+ni] = __builtin_amdgcn_mfma_f32_16x16x32_bf16(         \
          AF[mi][0], BF[ni][0], acc[(MB)+mi][(NB)+ni], 0, 0, 0);               \
      acc[(MB)+mi][(NB)+ni] = __builtin_amdgcn_mfma_f32_16x16x32_bf16(         \
          AF[mi][1], BF[ni][1], acc[(MB)+mi][(NB)+ni], 0, 0, 0); }             \
    __builtin_amdgcn_s_setprio(0);                                             \
  } while (0)

#define TILE(TV, CUR, NL) do {                                                 \
    /* Q0: rd A0,B0 | stage A0',B0' | BAR lgkm0 MM(00) vmcnt(6) BAR */         \
    RD_A(af, 0, CUR); RD_B(bf0, 0, CUR); SCHED0;                               \
    if (NL) { stA((TV) + 1, 0, (CUR) ^ 1); stB((TV) + 1, 0, (CUR) ^ 1); }      \
    SCHED0; SBAR; LGKM0; SCHED0;                                               \
    MM(af, bf0, 0, 0);                                                         \
    if (NL) { VMCNT6; } else { VMCNT2; }                                       \
    SCHED0; SBAR; SCHED0;                                                      \
    /* Q1: rd B1 | stage B1',A1' | BAR lgkm0 MM(01) vmcnt(8) BAR */            \
    RD_B(bf1, 1, CUR); SCHED0;                                                 \
    if (NL) { stB((TV) + 1, 1, (CUR) ^ 1); stA((TV) + 1, 1, (CUR) ^ 1); }      \
    SCHED0; SBAR; LGKM0; SCHED0;                                               \
    MM(af, bf1, 0, 2);                                                         \
    if (NL) { VMCNT8; } else { VMCNT0; }                                       \
    SCHED0; SBAR; SCHED0;                                                      \
    /* Q2: rd A1 (overwrite A-set) | BAR lgkm0 MM(10)+MM(11) vmcnt(4) BAR */   \
    RD_A(af, 1, CUR); SCHED0;                                                  \
    SBAR; LGKM0; SCHED0;                                                       \
    MM(af, bf0, 4, 0);                                                         \
    MM(af, bf1, 4, 2);                                                         \
    if (NL) { VMCNT4; }                                                        \
    SCHED0; SBAR; SCHED0;                                                      \
  } while (0)

  // prologue: stage tile 0 half-tiles in consumption order A0,B0,B1,A1
  stA(0, 0, 0); stB(0, 0, 0); stB(0, 1, 0); stA(0, 1, 0);
  VMCNT4; SCHED0; SBAR;

  for (int t = 0; t < KT - 2; t += 2) {
    TILE(t, 0, true);
    TILE(t + 1, 1, true);
  }
  TILE(KT - 2, 0, true);
  TILE(KT - 1, 1, false);
#undef RD_A
#undef RD_B
#undef MM
#undef TILE

  __syncthreads();   // all LDS fragment reads done; reuse LDS for epilogue

  // ---- epilogue via per-wave 16KB LDS reshape -> coalesced stores ----
  char* ep = LB + w * 16384;
  const int rq = l >> 4;
  if (EPI != 2) {
    // stage bf16 [128 rows][64 cols], byte = row*128 + col*2, ^((row&7)<<4)
#pragma unroll
    for (int mi = 0; mi < 8; ++mi)
#pragma unroll
      for (int ni = 0; ni < 4; ++ni) {
        int cl = ni * 16 + fr;
        float bv = bias[n0 + wn * 64 + cl];
#pragma unroll
        for (int r = 0; r < 4; ++r) {
          float v = acc[mi][ni][r] + bv;
          if (EPI == 1) v = sigmoidf(v);
          int row = mi * 16 + rq * 4 + r;
          int byte = (row * 128 + cl * 2) ^ ((row & 7) << 4);
          *(unsigned short*)(ep + byte) = f2bf(v);
        }
      }
    LGKM0; SCHED0;
#pragma unroll
    for (int i = 0; i < 16; ++i) {
      int row = i * 8 + (l >> 3);
      int cb = (l & 7) * 16;
      int byte = (row * 128 + cb) ^ ((row & 7) << 4);
      short8 v = *(const short8*)(ep + byte);
      *(short8*)((unsigned short*)Cout + (m0 + wm * 128 + row) * ldc
                 + n0 + wn * 64 + (cb >> 1)) = v;
    }
  } else {
    // fp32: two passes of 64 rows, [64 rows][64 cols] f32, byte=row*256+col*4
#pragma unroll
    for (int p = 0; p < 2; ++p) {
#pragma unroll
      for (int mi = 0; mi < 4; ++mi)
#pragma unroll
        for (int ni = 0; ni < 4; ++ni) {
          int cl = ni * 16 + fr;
          float bv = bias[n0 + wn * 64 + cl];
#pragma unroll
          for (int r = 0; r < 4; ++r) {
            float v = acc[p * 4 + mi][ni][r] + bv;
            int row = mi * 16 + rq * 4 + r;   // 0..63
            int byte = (row * 256 + cl * 4) ^ ((row & 7) << 4);
            *(float*)(ep + byte) = v;
          }
        }
      LGKM0; SCHED0;
#pragma unroll
      for (int i = 0; i < 16; ++i) {
        int row = i * 4 + (l >> 4);
        int cb = (l & 15) * 16;
        int byte = (row * 256 + cb) ^ ((row & 7) << 4);
        f32x4 v = *(const f32x4*)(ep + byte);
        *(f32x4*)((float*)Cout + (m0 + wm * 128 + p * 64 + row) * ldc
                  + n0 + wn * 64 + (cb >> 2)) = v;
      }
      LGKM0; SCHED0;   // pass-1 reads drained before pass-2 overwrites
    }
  }
}

// ---------------- scan pass A: per-chunk decay product + local h ----------------
__global__ void scan_passA(const unsigned short* __restrict__ dtb,   // [M,D] bf16
                           const unsigned short* __restrict__ xz,    // [M,2D] bf16
                           float* __restrict__ P, float* __restrict__ Hl)
{
  int idx = blockIdx.x * blockDim.x + threadIdx.x;   // 0 .. 65535
  int d8 = idx & 127;
  int c  = (idx >> 7) & 31;
  int b  = idx >> 12;
  int d0 = d8 * 8;
  long mbase = (long)b * T_ + (long)c * CL;
  float h[8] = {0,0,0,0,0,0,0,0};
  float p[8] = {1,1,1,1,1,1,1,1};
  for (int t = 0; t < CL; ++t) {
    long m = mbase + t;
    ushort8 dv = *(const ushort8*)(dtb + m * D_ + d0);
    ushort8 xv = *(const ushort8*)(xz + m * (2 * D_) + d0);
#pragma unroll
    for (int j = 0; j < 8; ++j) {
      float dt = bf2f(dv[j]);
      float xp = bf2f(xv[j]);
      float om = 1.f - dt;
      h[j] = om * h[j] + dt * xp;
      p[j] *= om;
    }
  }
  long pb = ((long)(b * NC + c)) * D_ + d0;
#pragma unroll
  for (int j = 0; j < 8; ++j) { P[pb + j] = p[j]; Hl[pb + j] = h[j]; }
}

// ---------------- scan pass C: fold chunk summaries + replay, fuse sigmoid(gate) ----
__global__ void scan_passC(unsigned short* dts,                      // in: dt, out: s
                           const unsigned short* __restrict__ xz,    // [M,2D]
                           const float* __restrict__ h0,             // [B,D]
                           const float* __restrict__ P,
                           const float* __restrict__ Hl)
{
  int idx = blockIdx.x * blockDim.x + threadIdx.x;
  int d8 = idx & 127;
  int c  = (idx >> 7) & 31;
  int b  = idx >> 12;
  int d0 = d8 * 8;
  long mbase = (long)b * T_ + (long)c * CL;

  float h[8];
#pragma unroll
  for (int j = 0; j < 8; ++j) h[j] = h0[(long)b * D_ + d0 + j];

  for (int jc = 0; jc < c; ++jc) {
    long pb = ((long)(b * NC + jc)) * D_ + d0;
    float pj[8], hj[8];
    *(f32x4*)&pj[0] = *(const f32x4*)(P + pb);
    *(f32x4*)&pj[4] = *(const f32x4*)(P + pb + 4);
    *(f32x4*)&hj[0] = *(const f32x4*)(Hl + pb);
    *(f32x4*)&hj[4] = *(const f32x4*)(Hl + pb + 4);
#pragma unroll
    for (int j = 0; j < 8; ++j) h[j] = hj[j] + pj[j] * h[j];
  }

  for (int t = 0; t < CL; ++t) {
    long m = mbase + t;
    ushort8 dv = *(const ushort8*)(dts + m * D_ + d0);
    ushort8 xv = *(const ushort8*)(xz + m * (2 * D_) + d0);
    ushort8 gv = *(const ushort8*)(xz + m * (2 * D_) + D_ + d0);
    ushort8 ov;
#pragma unroll
    for (int j = 0; j < 8; ++j) {
      float dt = bf2f(dv[j]);
      float xp = bf2f(xv[j]);
      h[j] = (1.f - dt) * h[j] + dt * xp;
      float gt = bf2f(gv[j]);
      ov[j] = f2bf(h[j] * sigmoidf(gt));
    }
    *(ushort8*)(dts + m * D_ + d0) = ov;
  }
}

// ---------------- launch ----------------
extern "C" void kernel_launch(void* const* d_in, const int* in_sizes, int n_in,
                              void* d_out, int out_size, void* d_ws, size_t ws_size,
                              hipStream_t stream) {
  const float* x     = (const float*)d_in[0];
  const float* h0    = (const float*)d_in[1];
  const float* W_in  = (const float*)d_in[2];
  const float* b_in  = (const float*)d_in[3];
  const float* W_dt  = (const float*)d_in[4];
  const float* b_dt  = (const float*)d_in[5];
  const float* W_out = (const float*)d_in[6];
  const float* b_out = (const float*)d_in[7];
  float* out = (float*)d_out;

  char* ws = (char*)d_ws;
  const size_t OFF_XB    = 0;                     // x bf16        [M,D]    64 MiB
  const size_t OFF_WIN   = 67108864;              // W_in bf16     [2D,D]    4 MiB
  const size_t OFF_WDT   = 71303168;              // W_dt bf16     [D,D]     2 MiB
  const size_t OFF_WOUT  = 73400320;              // W_out bf16    [D,D]     2 MiB
  const size_t OFF_XZ    = 75497472;              // xz bf16       [M,2D]  128 MiB
  const size_t OFF_DTS   = 209715200;             // dt/s bf16     [M,D]    64 MiB
  const size_t OFF_P     = 276824064;             // P fp32        [B,NC,D]  2 MiB
  const size_t OFF_HL    = 278921216;             // Hl fp32       [B,NC,D]  2 MiB
  const size_t NEEDED    = 281018368;
  if (ws_size < NEEDED) return;

  unsigned short* xb    = (unsigned short*)(ws + OFF_XB);
  unsigned short* wbin  = (unsigned short*)(ws + OFF_WIN);
  unsigned short* wbdt  = (unsigned short*)(ws + OFF_WDT);
  unsigned short* wbout = (unsigned short*)(ws + OFF_WOUT);
  unsigned short* xz    = (unsigned short*)(ws + OFF_XZ);
  unsigned short* dts   = (unsigned short*)(ws + OFF_DTS);
  float* P  = (float*)(ws + OFF_P);
  float* Hl = (float*)(ws + OFF_HL);

  cvt_all<<<2048, 256, 0, stream>>>(x, xb, W_in, wbin, W_dt, wbdt, W_out, wbout);

  // xz = x @ W_in^T + b_in            (bf16 out, [M, 2D])
  gemm256<0><<<(M_/256)*(2*D_/256), 512, 0, stream>>>(xb, D_, wbin, b_in, xz, 2*D_, 2*D_/256);
  // dt = sigmoid(x_part @ W_dt^T + b_dt)   (bf16 out, [M, D]); x_part = xz[:, :D]
  gemm256<1><<<(M_/256)*(D_/256), 512, 0, stream>>>(xz, 2*D_, wbdt, b_dt, dts, D_, D_/256);
  // chunked scan
  scan_passA<<<256, 256, 0, stream>>>(dts, xz, P, Hl);
  scan_passC<<<256, 256, 0, stream>>>(dts, xz, h0, P, Hl);
  // y = s @ W_out^T + b_out           (fp32 out)
  gemm256<2><<<(M_/256)*(D_/256), 512, 0, stream>>>(dts, D_, wbout, b_out, out, D_, D_/256);
}

// Round 12
// 431.293 us; speedup vs baseline: 1.0603x; 1.0603x over previous
//
#include <hip/hip_runtime.h>
#include <hip/hip_bf16.h>
#include <cstdint>

typedef __attribute__((ext_vector_type(8))) short short8;
typedef __attribute__((ext_vector_type(4))) float f32x4;
typedef __attribute__((ext_vector_type(8))) unsigned short ushort8;

#define B_ 16
#define T_ 2048
#define D_ 1024
#define M_ (B_*T_)   // 32768
#define NC 64        // scan chunks (2 waves/SIMD occupancy)
#define CL 32        // chunk length = T_/NC

static __device__ __forceinline__ float bf2f(unsigned short u) {
  unsigned int x = ((unsigned int)u) << 16;
  return __builtin_bit_cast(float, x);
}
static __device__ __forceinline__ unsigned short f2bf(float f) {
  unsigned int x = __builtin_bit_cast(unsigned int, f);
  unsigned int r = x + 0x7fffu + ((x >> 16) & 1u);
  return (unsigned short)(r >> 16);
}
static __device__ __forceinline__ float sigmoidf(float v) {
  return 1.f / (1.f + __expf(-v));
}

typedef const __attribute__((address_space(1))) unsigned int* gas1_t;
typedef __attribute__((address_space(3))) unsigned int* las3_t;
static __device__ __forceinline__ void async_copy16(const void* g, void* l) {
  __builtin_amdgcn_global_load_lds((gas1_t)g, (las3_t)l, 16, 0, 0);
}

#define VMCNT8 asm volatile("s_waitcnt vmcnt(8)" ::: "memory")
#define VMCNT6 asm volatile("s_waitcnt vmcnt(6)" ::: "memory")
#define VMCNT4 asm volatile("s_waitcnt vmcnt(4)" ::: "memory")
#define VMCNT2 asm volatile("s_waitcnt vmcnt(2)" ::: "memory")
#define VMCNT0 asm volatile("s_waitcnt vmcnt(0)" ::: "memory")
#define LGKM0  asm volatile("s_waitcnt lgkmcnt(0)" ::: "memory")
#define SBAR   __builtin_amdgcn_s_barrier()
#define SCHED0 __builtin_amdgcn_sched_barrier(0)

// ---------------- merged fp32 -> bf16 converts (x8 vectorized, grid-stride) -------
__global__ void cvt_all(const float* __restrict__ x,  unsigned short* __restrict__ xb,
                        const float* __restrict__ w1, unsigned short* __restrict__ o1,
                        const float* __restrict__ w2, unsigned short* __restrict__ o2,
                        const float* __restrict__ w3, unsigned short* __restrict__ o3) {
  long i = (long)blockIdx.x * blockDim.x + threadIdx.x;
  long stride = (long)gridDim.x * blockDim.x;
  for (; i < 4718592; i += stride) {
    const float* src; unsigned short* dst; long off;
    if (i < 4194304)      { src = x;  dst = xb; off = i; }
    else if (i < 4456448) { src = w1; dst = o1; off = i - 4194304; }
    else if (i < 4587520) { src = w2; dst = o2; off = i - 4456448; }
    else                  { src = w3; dst = o3; off = i - 4587520; }
    const float4* p = (const float4*)(src + off * 8);
    float4 a = p[0], b = p[1];
    ushort8 o;
    o[0] = f2bf(a.x); o[1] = f2bf(a.y); o[2] = f2bf(a.z); o[3] = f2bf(a.w);
    o[4] = f2bf(b.x); o[5] = f2bf(b.y); o[6] = f2bf(b.z); o[7] = f2bf(b.w);
    *(ushort8*)(dst + off * 8) = o;
  }
}

// ---------------- 256x256 read-consume (m201-faithful) bf16 GEMM — R10 exact ------
// KT=16 K-tiles of BK=64. 8 waves (2M x 4N), per-wave out 128x64. LDS 128 KB dbuf.
// 3 phases/tile, each: {ds_reads | stage issue} BAR lgkm0 {MFMA cluster} vmcnt BAR
//   Q0: rd A0(8)+B0(4) | stage A0',B0'(nxt) | MM(00)        | vmcnt(6)
//   Q1: rd B1(4)       | stage B1',A1'(nxt) | MM(01)        | vmcnt(8)
//   Q2: rd A1(8, overwrite A-set)           | MM(10)+MM(11) | vmcnt(4)
// Ledger (steady): end-Q2 vmcnt(4) drains A0',B0'(t+1) for Q0; end-Q0 vmcnt(6)
//   drains B1(t); end-Q1 vmcnt(8) drains A1(t). Outstanding never < 4 (T4).
//   Tail tile: vmcnt(2)/vmcnt(0) at Q0/Q1. Prologue: 4 half-tiles, vmcnt(4).
template<int EPI>
__global__ __launch_bounds__(512, 2) void gemm256(
    const unsigned short* __restrict__ A, long lda,
    const unsigned short* __restrict__ Bw,
    const float* __restrict__ bias,
    void* __restrict__ Cout, long ldc,
    int nbx)
{
  constexpr int KT = 16;
  __shared__ __align__(16) unsigned short lds[65536];  // 128 KiB

  const int tid = threadIdx.x;
  const int l  = tid & 63, w = tid >> 6;
  const int wm = w >> 2, wn = w & 3;
  const int fr = l & 15, g = l >> 4;
  const int t8 = tid >> 3;
  const int c8x = ((l & 7) ^ (l >> 3)) << 4;     // staging source XOR (bytes)
  const int s0 = ((g ^ (fr & 7)) << 4);          // ds_read swizzle, kk=0
  const int aoff  = wm * 8192 + fr * 128 + s0;   // A frag base (within half), kk=0
  const int aoff1 = aoff ^ 0x40;                 // kk=1 (XOR, not add!)
  const int boff  = 65536 + wn * 4096 + fr * 128 + s0;  // B frag base, kk=0
  const int boff1 = boff ^ 0x40;                 // kk=1
  const int tB = (w >> 2) * 64 + (w & 3) * 8 + (l >> 3);

  const int nwg = gridDim.x;
  const int cpx = nwg >> 3;
  const int bid = blockIdx.x;
  const int swz = (bid & 7) * cpx + (bid >> 3);
  const long m0 = (long)(swz / nbx) * 256;
  const long n0 = (long)(swz % nbx) * 256;

  const char* Ab = (const char*)A;
  const char* Bb = (const char*)Bw;
  const long ldab = lda * 2;
  char* LB = (char*)lds;

  auto stA = [&](int kt, int h, int nb) {
    char* lb = LB + nb * 32768 + h * 16384 + w * 1024;
    long col = (long)kt * 128 + c8x;
    async_copy16(Ab + (m0 + h * 64 + t8) * ldab + col, lb);
    async_copy16(Ab + (m0 + 128 + h * 64 + t8) * ldab + col, lb + 8192);
  };
  auto stB = [&](int kt, int h, int nb) {
    char* lb = LB + 65536 + nb * 32768 + h * 16384 + w * 1024;
    long col = (long)kt * 128 + c8x;
    async_copy16(Bb + (n0 + tB + h * 32) * 2048 + col, lb);
    async_copy16(Bb + (n0 + tB + 128 + h * 32) * 2048 + col, lb + 8192);
  };

  f32x4 acc[8][4] = {};
  short8 af[4][2], bf0[2][2], bf1[2][2];

#define RD_A(DST, MH, CUR) do {                                                \
    const char* p0_ = LB + (CUR) * 32768 + (MH) * 16384 + aoff;                \
    const char* p1_ = LB + (CUR) * 32768 + (MH) * 16384 + aoff1;               \
    _Pragma("unroll") for (int mi = 0; mi < 4; ++mi) {                         \
      DST[mi][0] = *(const short8*)(p0_ + mi * 2048);                          \
      DST[mi][1] = *(const short8*)(p1_ + mi * 2048); }                        \
  } while (0)
#define RD_B(DST, NH, CUR) do {                                                \
    const char* p0_ = LB + (CUR) * 32768 + (NH) * 16384 + boff;                \
    const char* p1_ = LB + (CUR) * 32768 + (NH) * 16384 + boff1;               \
    _Pragma("unroll") for (int ni = 0; ni < 2; ++ni) {                         \
      DST[ni][0] = *(const short8*)(p0_ + ni * 2048);                          \
      DST[ni][1] = *(const short8*)(p1_ + ni * 2048); }                        \
  } while (0)
#define MM(AF, BF, MB, NB) do {                                                \
    __builtin_amdgcn_s_setprio(1);                                             \
    _Pragma("unroll") for (int mi = 0; mi < 4; ++mi)                           \
    _Pragma("unroll") for (int ni = 0; ni < 2; ++ni) {                         \
      acc[(MB)+mi][(NB)+ni] = __builtin_amdgcn_mfma_f32_16x16x32_bf16(         \
          AF[mi][0], BF[ni][0], acc[(MB)+mi][(NB)+ni], 0, 0, 0);               \
      acc[(MB)+mi][(NB)+ni] = __builtin_amdgcn_mfma_f32_16x16x32_bf16(         \
          AF[mi][1], BF[ni][1], acc[(MB)+mi][(NB)+ni], 0, 0, 0); }             \
    __builtin_amdgcn_s_setprio(0);                                             \
  } while (0)

  // prologue: stage tile 0 half-tiles in consumption order A0,B0,B1,A1
  stA(0, 0, 0); stB(0, 0, 0); stB(0, 1, 0); stA(0, 1, 0);
  VMCNT4; SCHED0; SBAR;

  for (int t = 0; t < KT; ++t) {
    const int cur = t & 1, nxt = cur ^ 1;
    const bool nl = (t + 1 < KT);
    // Q0: rd A0,B0 | stage A0',B0' | BAR lgkm0 MM(00) vmcnt(6) BAR
    RD_A(af, 0, cur); RD_B(bf0, 0, cur); SCHED0;
    if (nl) { stA(t + 1, 0, nxt); stB(t + 1, 0, nxt); } SCHED0;
    SBAR; LGKM0; SCHED0;
    MM(af, bf0, 0, 0);
    if (nl) { VMCNT6; } else { VMCNT2; }
    SCHED0; SBAR; SCHED0;
    // Q1: rd B1 | stage B1',A1' | BAR lgkm0 MM(01) vmcnt(8) BAR
    RD_B(bf1, 1, cur); SCHED0;
    if (nl) { stB(t + 1, 1, nxt); stA(t + 1, 1, nxt); } SCHED0;
    SBAR; LGKM0; SCHED0;
    MM(af, bf1, 0, 2);
    if (nl) { VMCNT8; } else { VMCNT0; }
    SCHED0; SBAR; SCHED0;
    // Q2: rd A1 (overwrite A-set) | BAR lgkm0 MM(10)+MM(11) vmcnt(4) BAR
    RD_A(af, 1, cur); SCHED0;
    SBAR; LGKM0; SCHED0;
    MM(af, bf0, 4, 0);
    MM(af, bf1, 4, 2);
    if (nl) { VMCNT4; }
    SCHED0; SBAR; SCHED0;
  }
#undef RD_A
#undef RD_B
#undef MM

  __syncthreads();   // all LDS fragment reads done; reuse LDS for epilogue

  // ---- epilogue via per-wave 16KB LDS reshape -> coalesced stores ----
  char* ep = LB + w * 16384;
  const int rq = l >> 4;
  if (EPI != 2) {
    // stage bf16 [128 rows][64 cols], byte = row*128 + col*2, ^((row&7)<<4)
#pragma unroll
    for (int mi = 0; mi < 8; ++mi)
#pragma unroll
      for (int ni = 0; ni < 4; ++ni) {
        int cl = ni * 16 + fr;
        float bv = bias[n0 + wn * 64 + cl];
#pragma unroll
        for (int r = 0; r < 4; ++r) {
          float v = acc[mi][ni][r] + bv;
          if (EPI == 1) v = sigmoidf(v);
          int row = mi * 16 + rq * 4 + r;
          int byte = (row * 128 + cl * 2) ^ ((row & 7) << 4);
          *(unsigned short*)(ep + byte) = f2bf(v);
        }
      }
    LGKM0; SCHED0;
#pragma unroll
    for (int i = 0; i < 16; ++i) {
      int row = i * 8 + (l >> 3);
      int cb = (l & 7) * 16;
      int byte = (row * 128 + cb) ^ ((row & 7) << 4);
      short8 v = *(const short8*)(ep + byte);
      *(short8*)((unsigned short*)Cout + (m0 + wm * 128 + row) * ldc
                 + n0 + wn * 64 + (cb >> 1)) = v;
    }
  } else {
    // fp32: two passes of 64 rows, [64 rows][64 cols] f32, byte=row*256+col*4
#pragma unroll
    for (int p = 0; p < 2; ++p) {
#pragma unroll
      for (int mi = 0; mi < 4; ++mi)
#pragma unroll
        for (int ni = 0; ni < 4; ++ni) {
          int cl = ni * 16 + fr;
          float bv = bias[n0 + wn * 64 + cl];
#pragma unroll
          for (int r = 0; r < 4; ++r) {
            float v = acc[p * 4 + mi][ni][r] + bv;
            int row = mi * 16 + rq * 4 + r;   // 0..63
            int byte = (row * 256 + cl * 4) ^ ((row & 7) << 4);
            *(float*)(ep + byte) = v;
          }
        }
      LGKM0; SCHED0;
#pragma unroll
      for (int i = 0; i < 16; ++i) {
        int row = i * 4 + (l >> 4);
        int cb = (l & 15) * 16;
        int byte = (row * 256 + cb) ^ ((row & 7) << 4);
        f32x4 v = *(const f32x4*)(ep + byte);
        *(f32x4*)((float*)Cout + (m0 + wm * 128 + p * 64 + row) * ldc
                  + n0 + wn * 64 + (cb >> 2)) = v;
      }
      LGKM0; SCHED0;   // pass-1 reads drained before pass-2 overwrites
    }
  }
}

// ---------------- scan pass A: per-chunk decay product + local h ----------------
// NC=64 chunks of CL=32 -> 131072 threads (2 waves/SIMD) for latency hiding.
__global__ void scan_passA(const unsigned short* __restrict__ dtb,   // [M,D] bf16
                           const unsigned short* __restrict__ xz,    // [M,2D] bf16
                           float* __restrict__ P, float* __restrict__ Hl)
{
  int idx = blockIdx.x * blockDim.x + threadIdx.x;   // 0 .. 131071
  int d8 = idx & 127;
  int c  = (idx >> 7) & (NC - 1);
  int b  = idx >> 13;
  int d0 = d8 * 8;
  long mbase = (long)b * T_ + (long)c * CL;
  float h[8] = {0,0,0,0,0,0,0,0};
  float p[8] = {1,1,1,1,1,1,1,1};
#pragma unroll 4
  for (int t = 0; t < CL; ++t) {
    long m = mbase + t;
    ushort8 dv = *(const ushort8*)(dtb + m * D_ + d0);
    ushort8 xv = *(const ushort8*)(xz + m * (2 * D_) + d0);
#pragma unroll
    for (int j = 0; j < 8; ++j) {
      float dt = bf2f(dv[j]);
      float xp = bf2f(xv[j]);
      float om = 1.f - dt;
      h[j] = om * h[j] + dt * xp;
      p[j] *= om;
    }
  }
  long pb = ((long)(b * NC + c)) * D_ + d0;
#pragma unroll
  for (int j = 0; j < 8; ++j) { P[pb + j] = p[j]; Hl[pb + j] = h[j]; }
}

// ---------------- scan pass C: fold chunk summaries + replay, fuse sigmoid(gate) ----
__global__ void scan_passC(unsigned short* dts,                      // in: dt, out: s
                           const unsigned short* __restrict__ xz,    // [M,2D]
                           const float* __restrict__ h0,             // [B,D]
                           const float* __restrict__ P,
                           const float* __restrict__ Hl)
{
  int idx = blockIdx.x * blockDim.x + threadIdx.x;
  int d8 = idx & 127;
  int c  = (idx >> 7) & (NC - 1);
  int b  = idx >> 13;
  int d0 = d8 * 8;
  long mbase = (long)b * T_ + (long)c * CL;

  float h[8];
#pragma unroll
  for (int j = 0; j < 8; ++j) h[j] = h0[(long)b * D_ + d0 + j];

  for (int jc = 0; jc < c; ++jc) {
    long pb = ((long)(b * NC + jc)) * D_ + d0;
    float pj[8], hj[8];
    *(f32x4*)&pj[0] = *(const f32x4*)(P + pb);
    *(f32x4*)&pj[4] = *(const f32x4*)(P + pb + 4);
    *(f32x4*)&hj[0] = *(const f32x4*)(Hl + pb);
    *(f32x4*)&hj[4] = *(const f32x4*)(Hl + pb + 4);
#pragma unroll
    for (int j = 0; j < 8; ++j) h[j] = hj[j] + pj[j] * h[j];
  }

#pragma unroll 4
  for (int t = 0; t < CL; ++t) {
    long m = mbase + t;
    ushort8 dv = *(const ushort8*)(dts + m * D_ + d0);
    ushort8 xv = *(const ushort8*)(xz + m * (2 * D_) + d0);
    ushort8 gv = *(const ushort8*)(xz + m * (2 * D_) + D_ + d0);
    ushort8 ov;
#pragma unroll
    for (int j = 0; j < 8; ++j) {
      float dt = bf2f(dv[j]);
      float xp = bf2f(xv[j]);
      h[j] = (1.f - dt) * h[j] + dt * xp;
      float gt = bf2f(gv[j]);
      ov[j] = f2bf(h[j] * sigmoidf(gt));
    }
    *(ushort8*)(dts + m * D_ + d0) = ov;
  }
}

// ---------------- launch ----------------
extern "C" void kernel_launch(void* const* d_in, const int* in_sizes, int n_in,
                              void* d_out, int out_size, void* d_ws, size_t ws_size,
                              hipStream_t stream) {
  const float* x     = (const float*)d_in[0];
  const float* h0    = (const float*)d_in[1];
  const float* W_in  = (const float*)d_in[2];
  const float* b_in  = (const float*)d_in[3];
  const float* W_dt  = (const float*)d_in[4];
  const float* b_dt  = (const float*)d_in[5];
  const float* W_out = (const float*)d_in[6];
  const float* b_out = (const float*)d_in[7];
  float* out = (float*)d_out;

  char* ws = (char*)d_ws;
  const size_t OFF_XB    = 0;                     // x bf16        [M,D]    64 MiB
  const size_t OFF_WIN   = 67108864;              // W_in bf16     [2D,D]    4 MiB
  const size_t OFF_WDT   = 71303168;              // W_dt bf16     [D,D]     2 MiB
  const size_t OFF_WOUT  = 73400320;              // W_out bf16    [D,D]     2 MiB
  const size_t OFF_XZ    = 75497472;              // xz bf16       [M,2D]  128 MiB
  const size_t OFF_DTS   = 209715200;             // dt/s bf16     [M,D]    64 MiB
  const size_t NEEDED    = 281018368;
  if (ws_size < NEEDED) return;

  unsigned short* xb    = (unsigned short*)(ws + OFF_XB);
  unsigned short* wbin  = (unsigned short*)(ws + OFF_WIN);
  unsigned short* wbdt  = (unsigned short*)(ws + OFF_WDT);
  unsigned short* wbout = (unsigned short*)(ws + OFF_WOUT);
  unsigned short* xz    = (unsigned short*)(ws + OFF_XZ);
  unsigned short* dts   = (unsigned short*)(ws + OFF_DTS);
  // P/Hl (fp32, [B][NC][D] = 4 MiB each) live in the xb region, which is dead
  // after GEMM1 (stream-serial; only GEMM1 reads xb). No workspace growth.
  float* P  = (float*)(ws + OFF_XB);
  float* Hl = (float*)(ws + OFF_XB + 4194304);

  cvt_all<<<2048, 256, 0, stream>>>(x, xb, W_in, wbin, W_dt, wbdt, W_out, wbout);

  // xz = x @ W_in^T + b_in            (bf16 out, [M, 2D])
  gemm256<0><<<(M_/256)*(2*D_/256), 512, 0, stream>>>(xb, D_, wbin, b_in, xz, 2*D_, 2*D_/256);
  // dt = sigmoid(x_part @ W_dt^T + b_dt)   (bf16 out, [M, D]); x_part = xz[:, :D]
  gemm256<1><<<(M_/256)*(D_/256), 512, 0, stream>>>(xz, 2*D_, wbdt, b_dt, dts, D_, D_/256);
  // chunked scan (NC=64, CL=32)
  scan_passA<<<512, 256, 0, stream>>>(dts, xz, P, Hl);
  scan_passC<<<512, 256, 0, stream>>>(dts, xz, h0, P, Hl);
  // y = s @ W_out^T + b_out           (fp32 out)
  gemm256<2><<<(M_/256)*(D_/256), 512, 0, stream>>>(dts, D_, wbout, b_out, out, D_, D_/256);
}